// Round 1
// baseline (978.069 us; speedup 1.0000x reference)
//
#include <hip/hip_runtime.h>

#define N_TOK 2048
#define H_DIM 2048
#define I_DIM 1408
#define E_EXP 64
#define G_GRP 8

typedef __bf16 bf16x8 __attribute__((ext_vector_type(8)));
typedef float f32x4 __attribute__((ext_vector_type(4)));

__device__ __forceinline__ unsigned short f2bf(float f) {
    unsigned int u = __builtin_bit_cast(unsigned int, f);
    u += 0x7fffu + ((u >> 16) & 1u);   // RNE
    return (unsigned short)(u >> 16);
}

__device__ __forceinline__ void gl_lds16(const void* g, void* l) {
    __builtin_amdgcn_global_load_lds(
        (const __attribute__((address_space(1))) unsigned int*)g,
        (__attribute__((address_space(3))) unsigned int*)l, 16, 0, 0);
}

// XOR-swizzled LDS chunk addressing: slot(row,c) = row*8 + (c ^ (row&7)); 16B chunks.
__device__ __forceinline__ bf16x8 lds_frag(const unsigned short* sm, int row, int c) {
    return *(const bf16x8*)&sm[(row * 8 + (c ^ (row & 7))) * 8];
}

// ---------------- gate_w transpose: [64][2048] -> gwT [2048][64] ----------------
__global__ __launch_bounds__(256) void k_transpose(const float* __restrict__ gw,
                                                   float* __restrict__ gwT) {
    int i = blockIdx.x * 256 + threadIdx.x;   // 131072 total
    int h = i >> 6, e = i & 63;
    gwT[i] = gw[e * H_DIM + h];
}

// ---------------- fp32 -> bf16 weight conversion ----------------
__global__ __launch_bounds__(256) void k_cvt(const float* __restrict__ in,
                                             unsigned short* __restrict__ out, int n4) {
    int i = blockIdx.x * 256 + threadIdx.x;
    if (i >= n4) return;
    float4 v = ((const float4*)in)[i];
    ushort4 o;
    o.x = f2bf(v.x); o.y = f2bf(v.y); o.z = f2bf(v.z); o.w = f2bf(v.w);
    ((ushort4*)out)[i] = o;
}

// ---------------- gating: logits (f64 acc) + softmax + top8 + group softmax ----------------
// block = 512 (8 waves), 8 tokens per block. Phase 1: wave w accumulates h-slice w for
// all 8 tokens. Phase 2: wave w = token w, lane = expert.
__global__ __launch_bounds__(512) void k_gating(const float* __restrict__ x,
                                                const float* __restrict__ gwT,
                                                float* __restrict__ soft,
                                                float* __restrict__ scal) {
    __shared__ double smAcc[8][8][64];   // [h-slice wave][tok][expert]
    int t = threadIdx.x, wid = t >> 6, lane = t & 63;
    int n0 = blockIdx.x * 8;

    double acc[8];
#pragma unroll
    for (int k = 0; k < 8; ++k) acc[k] = 0.0;
    int h0 = wid * 256;
    for (int h = h0; h < h0 + 256; ++h) {
        float gv = gwT[h * 64 + lane];
#pragma unroll
        for (int tok = 0; tok < 8; ++tok)
            acc[tok] += (double)x[(size_t)(n0 + tok) * H_DIM + h] * (double)gv;
    }
#pragma unroll
    for (int tok = 0; tok < 8; ++tok) smAcc[wid][tok][lane] = acc[tok];
    __syncthreads();

    double lg = 0.0;
#pragma unroll
    for (int w2 = 0; w2 < 8; ++w2) lg += smAcc[w2][wid][lane];
    float logit = (float)lg;

    // softmax over 64 experts
    float mx = logit;
#pragma unroll
    for (int d = 1; d < 64; d <<= 1) mx = fmaxf(mx, __shfl_xor(mx, d));
    float ex = expf(logit - mx);
    float sm = ex;
#pragma unroll
    for (int d = 1; d < 64; d <<= 1) sm += __shfl_xor(sm, d);
    float prob = ex / sm;

    // top-8 (lowest index wins ties, matching lax.top_k)
    float cur = prob, w = 0.0f;
#pragma unroll
    for (int it = 0; it < 8; ++it) {
        float m = cur;
#pragma unroll
        for (int d = 1; d < 64; d <<= 1) m = fmaxf(m, __shfl_xor(m, d));
        unsigned long long msk = __ballot(cur == m);
        int first = __ffsll(msk) - 1;
        if (lane == first) { w = prob; cur = -1.0f; }
    }
    // inv_map is identity (arange) -> flat position == expert id
    float wf = w;

    // per-group (8 lanes) sum + masked softmax
    float s8 = wf;
#pragma unroll
    for (int d = 1; d < 8; d <<= 1) s8 += __shfl_xor(s8, d);
    float v = (wf == 0.0f) ? -1000000000.0f : wf;
    float m8 = v;
#pragma unroll
    for (int d = 1; d < 8; d <<= 1) m8 = fmaxf(m8, __shfl_xor(m8, d));
    float e8 = expf(v - m8);
    float q8 = e8;
#pragma unroll
    for (int d = 1; d < 8; d <<= 1) q8 += __shfl_xor(q8, d);

    int n = n0 + wid;
    soft[(size_t)n * 64 + lane] = e8 / q8;
    if ((lane & 7) == 0) scal[(size_t)n * 8 + (lane >> 3)] = s8;
}

// ---------------- xg[g][n][h] = bf16(x[n,h] + sum_s soft[n,g,s]*mu[g,h,s]) ----------------
__global__ __launch_bounds__(256) void k_xg(const float* __restrict__ x,
                                            const float* __restrict__ muw,
                                            const float* __restrict__ soft,
                                            unsigned short* __restrict__ xg) {
    int g = blockIdx.z, h0 = blockIdx.y * 256, n0 = blockIdx.x * 128;
    __shared__ float smMu[8][256];
    __shared__ float smSf[128][8];
    int t = threadIdx.x;
    {
        const float* p = muw + ((size_t)g * H_DIM + h0 + t) * 8;
#pragma unroll
        for (int s = 0; s < 8; ++s) smMu[s][t] = p[s];
        int r = t >> 1, s4 = (t & 1) * 4;
        float4 sv = *(const float4*)&soft[(size_t)(n0 + r) * 64 + g * 8 + s4];
        smSf[r][s4 + 0] = sv.x; smSf[r][s4 + 1] = sv.y;
        smSf[r][s4 + 2] = sv.z; smSf[r][s4 + 3] = sv.w;
    }
    __syncthreads();
    const float* xp = x + (size_t)n0 * H_DIM + h0 + t;
    unsigned short* op = xg + ((size_t)g * N_TOK + n0) * H_DIM + h0 + t;
    for (int r = 0; r < 128; ++r) {
        float corr = 0.0f;
#pragma unroll
        for (int s = 0; s < 8; ++s) corr += smSf[r][s] * smMu[s][t];
        op[(size_t)r * H_DIM] = f2bf(xp[(size_t)r * H_DIM] + corr);
    }
}

// ---------------- gemm1: a[g] = silu(xg_g @ Wg^T) * (xg_g @ Wu^T), bf16 out ----------------
// 128x128 tile, BK=64, fused gate+up, global_load_lds(16B) staging w/ XOR swizzle.
__global__ __launch_bounds__(256) void k_gemm1(const unsigned short* __restrict__ xg,
                                               const unsigned short* __restrict__ wg,
                                               const unsigned short* __restrict__ wu,
                                               unsigned short* __restrict__ aout) {
    int g = blockIdx.z, m0 = blockIdx.x * 128, i0 = blockIdx.y * 128;
    __shared__ __align__(16) unsigned short smA[8192], smG[8192], smU[8192];
    int t = threadIdx.x, wid = t >> 6, lane = t & 63;
    int r16 = lane & 15, quad = lane >> 4;
    int wm = wid >> 1, wn = wid & 1;

    const unsigned short* A  = xg + (size_t)g * N_TOK * H_DIM;
    const unsigned short* Bg = wg + (size_t)g * I_DIM * H_DIM;
    const unsigned short* Bu = wu + (size_t)g * I_DIM * H_DIM;

    f32x4 zero = {0.f, 0.f, 0.f, 0.f};
    f32x4 accg[4][4], accu[4][4];
#pragma unroll
    for (int mi = 0; mi < 4; ++mi)
#pragma unroll
        for (int ni = 0; ni < 4; ++ni) { accg[mi][ni] = zero; accu[mi][ni] = zero; }

    for (int k0 = 0; k0 < H_DIM; k0 += 64) {
#pragma unroll
        for (int j = 0; j < 4; ++j) {
            int issue = wid * 4 + j;
            int s = issue * 64 + lane;
            int row = s >> 3;
            int c = (s & 7) ^ (row & 7);
            gl_lds16(A  + (size_t)(m0 + row) * H_DIM + k0 + c * 8, &smA[issue * 512]);
            gl_lds16(Bg + (size_t)(i0 + row) * H_DIM + k0 + c * 8, &smG[issue * 512]);
            gl_lds16(Bu + (size_t)(i0 + row) * H_DIM + k0 + c * 8, &smU[issue * 512]);
        }
        __syncthreads();
#pragma unroll
        for (int kh = 0; kh < 2; ++kh) {
            int cc = kh * 4 + quad;
            bf16x8 af[4], bgf[4], buf_[4];
#pragma unroll
            for (int mi = 0; mi < 4; ++mi) af[mi]  = lds_frag(smA, wm * 64 + mi * 16 + r16, cc);
#pragma unroll
            for (int ni = 0; ni < 4; ++ni) { int rw = wn * 64 + ni * 16 + r16;
                bgf[ni] = lds_frag(smG, rw, cc); buf_[ni] = lds_frag(smU, rw, cc); }
#pragma unroll
            for (int mi = 0; mi < 4; ++mi)
#pragma unroll
                for (int ni = 0; ni < 4; ++ni) {
                    accg[mi][ni] = __builtin_amdgcn_mfma_f32_16x16x32_bf16(af[mi], bgf[ni], accg[mi][ni], 0, 0, 0);
                    accu[mi][ni] = __builtin_amdgcn_mfma_f32_16x16x32_bf16(af[mi], buf_[ni], accu[mi][ni], 0, 0, 0);
                }
        }
        __syncthreads();
    }

    unsigned short* ao = aout + (size_t)g * N_TOK * I_DIM;
#pragma unroll
    for (int mi = 0; mi < 4; ++mi)
#pragma unroll
        for (int ni = 0; ni < 4; ++ni)
#pragma unroll
            for (int r = 0; r < 4; ++r) {
                float gv = accg[mi][ni][r], uv = accu[mi][ni][r];
                float sv = gv / (1.0f + __expf(-gv));
                int row = m0 + wm * 64 + mi * 16 + quad * 4 + r;
                int col = i0 + wn * 64 + ni * 16 + r16;
                ao[(size_t)row * I_DIM + col] = f2bf(sv * uv);
            }
}

// ---------------- gemm2: y[n,h] += sum_g scalar[n,g] * (a_g @ Wd_g^T) ----------------
// z = 4 slices of 2 groups; per-group acc scaled into y-acc in regs; atomicAdd to d_out.
__global__ __launch_bounds__(256) void k_gemm2(const unsigned short* __restrict__ aIn,
                                               const unsigned short* __restrict__ wd,
                                               const float* __restrict__ scal,
                                               float* __restrict__ out) {
    int m0 = blockIdx.x * 128, h0 = blockIdx.y * 128, g0 = blockIdx.z * 2;
    __shared__ __align__(16) unsigned short smA[8192], smB[8192];
    __shared__ float smS[128][2];
    int t = threadIdx.x, wid = t >> 6, lane = t & 63;
    int r16 = lane & 15, quad = lane >> 4;
    int wm = wid >> 1, wn = wid & 1;
    {
        int r = t >> 1, j = t & 1;
        smS[r][j] = scal[(size_t)(m0 + r) * 8 + g0 + j];
    }
    f32x4 zero = {0.f, 0.f, 0.f, 0.f};
    f32x4 accy[4][4];
#pragma unroll
    for (int mi = 0; mi < 4; ++mi)
#pragma unroll
        for (int ni = 0; ni < 4; ++ni) accy[mi][ni] = zero;

    for (int gj = 0; gj < 2; ++gj) {
        int g = g0 + gj;
        const unsigned short* A = aIn + (size_t)g * N_TOK * I_DIM;
        const unsigned short* B = wd  + (size_t)g * H_DIM * I_DIM;
        f32x4 acc[4][4];
#pragma unroll
        for (int mi = 0; mi < 4; ++mi)
#pragma unroll
            for (int ni = 0; ni < 4; ++ni) acc[mi][ni] = zero;

        for (int k0 = 0; k0 < I_DIM; k0 += 64) {
#pragma unroll
            for (int j = 0; j < 4; ++j) {
                int issue = wid * 4 + j;
                int s = issue * 64 + lane;
                int row = s >> 3;
                int c = (s & 7) ^ (row & 7);
                gl_lds16(A + (size_t)(m0 + row) * I_DIM + k0 + c * 8, &smA[issue * 512]);
                gl_lds16(B + (size_t)(h0 + row) * I_DIM + k0 + c * 8, &smB[issue * 512]);
            }
            __syncthreads();
#pragma unroll
            for (int kh = 0; kh < 2; ++kh) {
                int cc = kh * 4 + quad;
                bf16x8 af[4], bf_[4];
#pragma unroll
                for (int mi = 0; mi < 4; ++mi) af[mi]  = lds_frag(smA, wm * 64 + mi * 16 + r16, cc);
#pragma unroll
                for (int ni = 0; ni < 4; ++ni) bf_[ni] = lds_frag(smB, wn * 64 + ni * 16 + r16, cc);
#pragma unroll
                for (int mi = 0; mi < 4; ++mi)
#pragma unroll
                    for (int ni = 0; ni < 4; ++ni)
                        acc[mi][ni] = __builtin_amdgcn_mfma_f32_16x16x32_bf16(af[mi], bf_[ni], acc[mi][ni], 0, 0, 0);
            }
            __syncthreads();
        }
#pragma unroll
        for (int mi = 0; mi < 4; ++mi)
#pragma unroll
            for (int ni = 0; ni < 4; ++ni)
#pragma unroll
                for (int r = 0; r < 4; ++r) {
                    float sc = smS[wm * 64 + mi * 16 + quad * 4 + r][gj];
                    accy[mi][ni][r] += sc * acc[mi][ni][r];
                }
    }
#pragma unroll
    for (int mi = 0; mi < 4; ++mi)
#pragma unroll
        for (int ni = 0; ni < 4; ++ni)
#pragma unroll
            for (int r = 0; r < 4; ++r) {
                int row = m0 + wm * 64 + mi * 16 + quad * 4 + r;
                int col = h0 + wn * 64 + ni * 16 + r16;
                atomicAdd(&out[(size_t)row * H_DIM + col], accy[mi][ni][r]);
            }
}

extern "C" void kernel_launch(void* const* d_in, const int* in_sizes, int n_in,
                              void* d_out, int out_size, void* d_ws, size_t ws_size,
                              hipStream_t stream) {
    const float* x   = (const float*)d_in[0];
    const float* gw  = (const float*)d_in[1];
    const float* mu  = (const float*)d_in[2];
    const float* wgp = (const float*)d_in[3];
    const float* wup = (const float*)d_in[4];
    const float* wdp = (const float*)d_in[5];
    float* out = (float*)d_out;
    char* ws = (char*)d_ws;

    // workspace layout (241.1 MB total)
    float* gwT  = (float*)(ws + 0);                      // 512 KB
    float* soft = (float*)(ws + 524288);                 // 512 KB
    float* scal = (float*)(ws + 1048576);                // 64 KB
    unsigned short* wgB = (unsigned short*)(ws + 1114112);    // 44 MB
    unsigned short* wuB = (unsigned short*)(ws + 47251456);   // 44 MB
    unsigned short* wdB = (unsigned short*)(ws + 93388800);   // 44 MB
    unsigned short* xg  = (unsigned short*)(ws + 139526144);  // 64 MB
    unsigned short* aB  = (unsigned short*)(ws + 206635008);  // 44 MB

    hipMemsetAsync(d_out, 0, (size_t)N_TOK * H_DIM * sizeof(float), stream);
    k_transpose<<<512, 256, 0, stream>>>(gw, gwT);
    int n4 = G_GRP * I_DIM * H_DIM / 4;
    k_cvt<<<(n4 + 255) / 256, 256, 0, stream>>>(wgp, wgB, n4);
    k_cvt<<<(n4 + 255) / 256, 256, 0, stream>>>(wup, wuB, n4);
    k_cvt<<<(n4 + 255) / 256, 256, 0, stream>>>(wdp, wdB, n4);
    k_gating<<<N_TOK / 8, 512, 0, stream>>>(x, gwT, soft, scal);
    k_xg<<<dim3(16, 8, 8), 256, 0, stream>>>(x, mu, soft, xg);
    k_gemm1<<<dim3(16, 11, 8), 256, 0, stream>>>(xg, wgB, wuB, aB);
    k_gemm2<<<dim3(16, 16, 4), 256, 0, stream>>>(aB, wdB, scal, out);
}

// Round 2
// 851.276 us; speedup vs baseline: 1.1489x; 1.1489x over previous
//
#include <hip/hip_runtime.h>

#define N_TOK 2048
#define H_DIM 2048
#define I_DIM 1408
#define E_EXP 64
#define G_GRP 8
#define KTOT  (G_GRP * I_DIM)   // 11264

typedef __bf16 bf16x8 __attribute__((ext_vector_type(8)));
typedef float f32x4 __attribute__((ext_vector_type(4)));

__device__ __forceinline__ unsigned short f2bf(float f) {
    unsigned int u = __builtin_bit_cast(unsigned int, f);
    u += 0x7fffu + ((u >> 16) & 1u);   // RNE
    return (unsigned short)(u >> 16);
}

__device__ __forceinline__ float bf2f(unsigned short s) {
    return __builtin_bit_cast(float, (unsigned int)s << 16);
}

__device__ __forceinline__ void gl_lds16(const void* g, void* l) {
    __builtin_amdgcn_global_load_lds(
        (const __attribute__((address_space(1))) unsigned int*)g,
        (__attribute__((address_space(3))) unsigned int*)l, 16, 0, 0);
}

// XOR-swizzled LDS chunk addressing: slot(row,c) = row*8 + (c ^ (row&7)); 16B chunks.
__device__ __forceinline__ bf16x8 lds_frag(const unsigned short* sm, int row, int c) {
    return *(const bf16x8*)&sm[(row * 8 + (c ^ (row & 7))) * 8];
}

// ---------------- gate_w transpose: [64][2048] -> gwT [2048][64] ----------------
__global__ __launch_bounds__(256) void k_transpose(const float* __restrict__ gw,
                                                   float* __restrict__ gwT) {
    int i = blockIdx.x * 256 + threadIdx.x;
    int h = i >> 6, e = i & 63;
    gwT[i] = gw[e * H_DIM + h];
}

// ---------------- fp32 -> bf16 weight conversion (layout-preserving) ----------------
__global__ __launch_bounds__(256) void k_cvt(const float* __restrict__ in,
                                             unsigned short* __restrict__ out, int n4) {
    int i = blockIdx.x * 256 + threadIdx.x;
    if (i >= n4) return;
    float4 v = ((const float4*)in)[i];
    ushort4 o;
    o.x = f2bf(v.x); o.y = f2bf(v.y); o.z = f2bf(v.z); o.w = f2bf(v.w);
    ((ushort4*)out)[i] = o;
}

// ------- down-proj cvt + transpose: wd[g][h][i] (f32) -> wdB[h][g*I+i] (bf16) -------
__global__ __launch_bounds__(256) void k_cvt_wd(const float* __restrict__ in,
                                                unsigned short* __restrict__ out) {
    int idx = blockIdx.x * 256 + threadIdx.x;          // 5,767,168 total
    int i4 = idx % (I_DIM / 4);
    int h  = (idx / (I_DIM / 4)) & (H_DIM - 1);
    int g  = idx / ((I_DIM / 4) * H_DIM);
    float4 v = ((const float4*)(in + ((size_t)g * H_DIM + h) * I_DIM))[i4];
    ushort4 o;
    o.x = f2bf(v.x); o.y = f2bf(v.y); o.z = f2bf(v.z); o.w = f2bf(v.w);
    ((ushort4*)(out + ((size_t)h * G_GRP + g) * I_DIM))[i4] = o;
}

// ---------------- gating: logits (f64 acc) + softmax + top8 + group softmax ----------------
__global__ __launch_bounds__(512) void k_gating(const float* __restrict__ x,
                                                const float* __restrict__ gwT,
                                                float* __restrict__ soft,
                                                float* __restrict__ scal) {
    __shared__ double smAcc[8][8][64];
    int t = threadIdx.x, wid = t >> 6, lane = t & 63;
    int n0 = blockIdx.x * 8;

    double acc[8];
#pragma unroll
    for (int k = 0; k < 8; ++k) acc[k] = 0.0;
    int h0 = wid * 256;
    for (int h = h0; h < h0 + 256; ++h) {
        float gv = gwT[h * 64 + lane];
#pragma unroll
        for (int tok = 0; tok < 8; ++tok)
            acc[tok] += (double)x[(size_t)(n0 + tok) * H_DIM + h] * (double)gv;
    }
#pragma unroll
    for (int tok = 0; tok < 8; ++tok) smAcc[wid][tok][lane] = acc[tok];
    __syncthreads();

    double lg = 0.0;
#pragma unroll
    for (int w2 = 0; w2 < 8; ++w2) lg += smAcc[w2][wid][lane];
    float logit = (float)lg;

    float mx = logit;
#pragma unroll
    for (int d = 1; d < 64; d <<= 1) mx = fmaxf(mx, __shfl_xor(mx, d));
    float ex = expf(logit - mx);
    float sm = ex;
#pragma unroll
    for (int d = 1; d < 64; d <<= 1) sm += __shfl_xor(sm, d);
    float prob = ex / sm;

    float cur = prob, w = 0.0f;
#pragma unroll
    for (int it = 0; it < 8; ++it) {
        float m = cur;
#pragma unroll
        for (int d = 1; d < 64; d <<= 1) m = fmaxf(m, __shfl_xor(m, d));
        unsigned long long msk = __ballot(cur == m);
        int first = __ffsll(msk) - 1;
        if (lane == first) { w = prob; cur = -1.0f; }
    }
    float wf = w;

    float s8 = wf;
#pragma unroll
    for (int d = 1; d < 8; d <<= 1) s8 += __shfl_xor(s8, d);
    float v = (wf == 0.0f) ? -1000000000.0f : wf;
    float m8 = v;
#pragma unroll
    for (int d = 1; d < 8; d <<= 1) m8 = fmaxf(m8, __shfl_xor(m8, d));
    float e8 = expf(v - m8);
    float q8 = e8;
#pragma unroll
    for (int d = 1; d < 8; d <<= 1) q8 += __shfl_xor(q8, d);

    int n = n0 + wid;
    soft[(size_t)n * 64 + lane] = e8 / q8;
    if ((lane & 7) == 0) scal[(size_t)n * 8 + (lane >> 3)] = s8;
}

// ---------------- xg[g][n][h] = bf16(x[n,h] + sum_s soft[n,g,s]*mu[g,h,s]) ----------------
__global__ __launch_bounds__(256) void k_xg(const float* __restrict__ x,
                                            const float* __restrict__ muw,
                                            const float* __restrict__ soft,
                                            unsigned short* __restrict__ xg) {
    int g = blockIdx.z, h0 = blockIdx.y * 256, n0 = blockIdx.x * 128;
    __shared__ float smMu[8][256];
    __shared__ float smSf[128][8];
    int t = threadIdx.x;
    {
        const float* p = muw + ((size_t)g * H_DIM + h0 + t) * 8;
#pragma unroll
        for (int s = 0; s < 8; ++s) smMu[s][t] = p[s];
        int r = t >> 1, s4 = (t & 1) * 4;
        float4 sv = *(const float4*)&soft[(size_t)(n0 + r) * 64 + g * 8 + s4];
        smSf[r][s4 + 0] = sv.x; smSf[r][s4 + 1] = sv.y;
        smSf[r][s4 + 2] = sv.z; smSf[r][s4 + 3] = sv.w;
    }
    __syncthreads();
    const float* xp = x + (size_t)n0 * H_DIM + h0 + t;
    unsigned short* op = xg + ((size_t)g * N_TOK + n0) * H_DIM + h0 + t;
    for (int r = 0; r < 128; ++r) {
        float corr = 0.0f;
#pragma unroll
        for (int s = 0; s < 8; ++s) corr += smSf[r][s] * smMu[s][t];
        op[(size_t)r * H_DIM] = f2bf(xp[(size_t)r * H_DIM] + corr);
    }
}

// ---------------- gemm1 (m97-shape, unfused): one 128x128 tile, K=2048, BK=64 ----------------
// IS_UP=false: gate = xg_g @ Wg^T  -> aB (bf16)
// IS_UP=true : a'   = scal * silu(gate) * (xg_g @ Wu^T) -> aB in place
// Grid: 1408 1-D blocks; g = blk & 7 pins each group to one XCD (L2 locality).
// aB layout [n][g*I+i] so gemm2 is a flat K=11264 GEMM.
template<bool IS_UP>
__global__ __launch_bounds__(256) void k_gemm1(const unsigned short* __restrict__ xg,
                                               const unsigned short* __restrict__ w,
                                               const float* __restrict__ scal,
                                               unsigned short* __restrict__ aB) {
    int f = blockIdx.x;
    int g = f & 7, r = f >> 3;
    int m0 = (r & 15) * 128, i0 = (r >> 4) * 128;
    __shared__ __align__(16) unsigned short smA[8192], smB[8192];
    __shared__ float smS[128];
    int t = threadIdx.x, wid = t >> 6, lane = t & 63;
    int r16 = lane & 15, quad = lane >> 4;
    int wm = wid >> 1, wn = wid & 1;

    if (IS_UP && t < 128) smS[t] = scal[(size_t)(m0 + t) * 8 + g];

    const unsigned short* A = xg + (size_t)g * N_TOK * H_DIM;
    const unsigned short* B = w  + (size_t)g * I_DIM * H_DIM;

    f32x4 zero = {0.f, 0.f, 0.f, 0.f};
    f32x4 acc[4][4];
#pragma unroll
    for (int mi = 0; mi < 4; ++mi)
#pragma unroll
        for (int ni = 0; ni < 4; ++ni) acc[mi][ni] = zero;

    for (int k0 = 0; k0 < H_DIM; k0 += 64) {
#pragma unroll
        for (int j = 0; j < 4; ++j) {
            int issue = wid * 4 + j;
            int s = issue * 64 + lane;
            int row = s >> 3;
            int c = (s & 7) ^ (row & 7);
            gl_lds16(A + (size_t)(m0 + row) * H_DIM + k0 + c * 8, &smA[issue * 512]);
            gl_lds16(B + (size_t)(i0 + row) * H_DIM + k0 + c * 8, &smB[issue * 512]);
        }
        __syncthreads();
#pragma unroll
        for (int kh = 0; kh < 2; ++kh) {
            int cc = kh * 4 + quad;
            bf16x8 af[4], bf_[4];
#pragma unroll
            for (int mi = 0; mi < 4; ++mi) af[mi]  = lds_frag(smA, wm * 64 + mi * 16 + r16, cc);
#pragma unroll
            for (int ni = 0; ni < 4; ++ni) bf_[ni] = lds_frag(smB, wn * 64 + ni * 16 + r16, cc);
#pragma unroll
            for (int mi = 0; mi < 4; ++mi)
#pragma unroll
                for (int ni = 0; ni < 4; ++ni)
                    acc[mi][ni] = __builtin_amdgcn_mfma_f32_16x16x32_bf16(af[mi], bf_[ni], acc[mi][ni], 0, 0, 0);
        }
        __syncthreads();
    }

#pragma unroll
    for (int mi = 0; mi < 4; ++mi)
#pragma unroll
        for (int ni = 0; ni < 4; ++ni)
#pragma unroll
            for (int rr = 0; rr < 4; ++rr) {
                int rl = wm * 64 + mi * 16 + quad * 4 + rr;
                int row = m0 + rl;
                int col = i0 + wn * 64 + ni * 16 + r16;
                size_t pos = ((size_t)row * G_GRP + g) * I_DIM + col;
                if (!IS_UP) {
                    aB[pos] = f2bf(acc[mi][ni][rr]);
                } else {
                    float gv = bf2f(aB[pos]);
                    float sv = gv / (1.0f + __expf(-gv));
                    aB[pos] = f2bf(sv * acc[mi][ni][rr] * smS[rl]);
                }
            }
}

// ---------------- gemm2: y[n,h] = A'[n,:] . Wd'[h,:], K=11264, split-K=4 + atomicAdd ----------------
__global__ __launch_bounds__(256) void k_gemm2(const unsigned short* __restrict__ aB,
                                               const unsigned short* __restrict__ wd,
                                               float* __restrict__ out) {
    int m0 = blockIdx.x * 128, h0 = blockIdx.y * 128;
    int kbase = blockIdx.z * (KTOT / 4);
    __shared__ __align__(16) unsigned short smA[8192], smB[8192];
    int t = threadIdx.x, wid = t >> 6, lane = t & 63;
    int r16 = lane & 15, quad = lane >> 4;
    int wm = wid >> 1, wn = wid & 1;

    f32x4 zero = {0.f, 0.f, 0.f, 0.f};
    f32x4 acc[4][4];
#pragma unroll
    for (int mi = 0; mi < 4; ++mi)
#pragma unroll
        for (int ni = 0; ni < 4; ++ni) acc[mi][ni] = zero;

    for (int k0 = kbase; k0 < kbase + KTOT / 4; k0 += 64) {
#pragma unroll
        for (int j = 0; j < 4; ++j) {
            int issue = wid * 4 + j;
            int s = issue * 64 + lane;
            int row = s >> 3;
            int c = (s & 7) ^ (row & 7);
            gl_lds16(aB + (size_t)(m0 + row) * KTOT + k0 + c * 8, &smA[issue * 512]);
            gl_lds16(wd + (size_t)(h0 + row) * KTOT + k0 + c * 8, &smB[issue * 512]);
        }
        __syncthreads();
#pragma unroll
        for (int kh = 0; kh < 2; ++kh) {
            int cc = kh * 4 + quad;
            bf16x8 af[4], bf_[4];
#pragma unroll
            for (int mi = 0; mi < 4; ++mi) af[mi]  = lds_frag(smA, wm * 64 + mi * 16 + r16, cc);
#pragma unroll
            for (int ni = 0; ni < 4; ++ni) bf_[ni] = lds_frag(smB, wn * 64 + ni * 16 + r16, cc);
#pragma unroll
            for (int mi = 0; mi < 4; ++mi)
#pragma unroll
                for (int ni = 0; ni < 4; ++ni)
                    acc[mi][ni] = __builtin_amdgcn_mfma_f32_16x16x32_bf16(af[mi], bf_[ni], acc[mi][ni], 0, 0, 0);
        }
        __syncthreads();
    }

#pragma unroll
    for (int mi = 0; mi < 4; ++mi)
#pragma unroll
        for (int ni = 0; ni < 4; ++ni)
#pragma unroll
            for (int rr = 0; rr < 4; ++rr) {
                int row = m0 + wm * 64 + mi * 16 + quad * 4 + rr;
                int col = h0 + wn * 64 + ni * 16 + r16;
                atomicAdd(&out[(size_t)row * H_DIM + col], acc[mi][ni][rr]);
            }
}

extern "C" void kernel_launch(void* const* d_in, const int* in_sizes, int n_in,
                              void* d_out, int out_size, void* d_ws, size_t ws_size,
                              hipStream_t stream) {
    const float* x   = (const float*)d_in[0];
    const float* gw  = (const float*)d_in[1];
    const float* mu  = (const float*)d_in[2];
    const float* wgp = (const float*)d_in[3];
    const float* wup = (const float*)d_in[4];
    const float* wdp = (const float*)d_in[5];
    float* out = (float*)d_out;
    char* ws = (char*)d_ws;

    // workspace layout (241.1 MB total)
    float* gwT  = (float*)(ws + 0);                      // 512 KB
    float* soft = (float*)(ws + 524288);                 // 512 KB
    float* scal = (float*)(ws + 1048576);                // 64 KB
    unsigned short* wgB = (unsigned short*)(ws + 1114112);    // 44 MB [g][i][h]
    unsigned short* wuB = (unsigned short*)(ws + 47251456);   // 44 MB [g][i][h]
    unsigned short* wdB = (unsigned short*)(ws + 93388800);   // 44 MB [h][g*I+i]
    unsigned short* xg  = (unsigned short*)(ws + 139526144);  // 64 MB [g][n][h]
    unsigned short* aB  = (unsigned short*)(ws + 206635008);  // 44 MB [n][g*I+i]

    hipMemsetAsync(d_out, 0, (size_t)N_TOK * H_DIM * sizeof(float), stream);
    k_transpose<<<512, 256, 0, stream>>>(gw, gwT);
    int n4 = G_GRP * I_DIM * H_DIM / 4;
    k_cvt<<<(n4 + 255) / 256, 256, 0, stream>>>(wgp, wgB, n4);
    k_cvt<<<(n4 + 255) / 256, 256, 0, stream>>>(wup, wuB, n4);
    k_cvt_wd<<<n4 / 256, 256, 0, stream>>>(wdp, wdB);
    k_gating<<<N_TOK / 8, 512, 0, stream>>>(x, gwT, soft, scal);
    k_xg<<<dim3(16, 8, 8), 256, 0, stream>>>(x, mu, soft, xg);
    k_gemm1<false><<<1408, 256, 0, stream>>>(xg, wgB, scal, aB);
    k_gemm1<true><<<1408, 256, 0, stream>>>(xg, wuB, scal, aB);
    k_gemm2<<<dim3(16, 16, 4), 256, 0, stream>>>(aB, wdB, out);
}

// Round 3
// 824.590 us; speedup vs baseline: 1.1861x; 1.0324x over previous
//
#include <hip/hip_runtime.h>

#define N_TOK 2048
#define H_DIM 2048
#define I_DIM 1408
#define E_EXP 64
#define G_GRP 8
#define KTOT  (G_GRP * I_DIM)   // 11264
#define NQ    (G_GRP * I_DIM * H_DIM / 4)   // quads per weight array = 5,767,168
#define NQB   (NQ / 256)                    // 22528 blocks per array

typedef __bf16 bf16x8 __attribute__((ext_vector_type(8)));
typedef float f32x4 __attribute__((ext_vector_type(4)));

__device__ __forceinline__ unsigned short f2bf(float f) {
    unsigned int u = __builtin_bit_cast(unsigned int, f);
    u += 0x7fffu + ((u >> 16) & 1u);   // RNE
    return (unsigned short)(u >> 16);
}

__device__ __forceinline__ void gl_lds16(const void* g, void* l) {
    __builtin_amdgcn_global_load_lds(
        (const __attribute__((address_space(1))) unsigned int*)g,
        (__attribute__((address_space(3))) unsigned int*)l, 16, 0, 0);
}

// XOR-swizzled LDS chunk addressing: slot(row,c) = row*8 + (c ^ (row&7)); 16B chunks.
__device__ __forceinline__ bf16x8 lds_frag(const unsigned short* sm, int row, int c) {
    return *(const bf16x8*)&sm[(row * 8 + (c ^ (row & 7))) * 8];
}

// ---------- prep: 3x fp32->bf16 weight cvt (+wd transpose) + gate_w transpose ----------
__global__ __launch_bounds__(256) void k_prep(const float* __restrict__ gw,
                                              const float* __restrict__ wgp,
                                              const float* __restrict__ wup,
                                              const float* __restrict__ wdp,
                                              float* __restrict__ gwT,
                                              unsigned short* __restrict__ wgB,
                                              unsigned short* __restrict__ wuB,
                                              unsigned short* __restrict__ wdB) {
    int b = blockIdx.x, t = threadIdx.x;
    if (b < 2 * NQB) {   // layout-preserving cvt of wg / wu
        const float* in = (b < NQB) ? wgp : wup;
        unsigned short* out = (b < NQB) ? wgB : wuB;
        int i = (b < NQB ? b : b - NQB) * 256 + t;
        float4 v = ((const float4*)in)[i];
        ushort4 o;
        o.x = f2bf(v.x); o.y = f2bf(v.y); o.z = f2bf(v.z); o.w = f2bf(v.w);
        ((ushort4*)out)[i] = o;
    } else if (b < 3 * NQB) {  // wd: [g][h][i] f32 -> [h][g*I+i] bf16
        int idx = (b - 2 * NQB) * 256 + t;
        int i4 = idx % (I_DIM / 4);
        int h  = (idx / (I_DIM / 4)) & (H_DIM - 1);
        int g  = idx / ((I_DIM / 4) * H_DIM);
        float4 v = ((const float4*)(wdp + ((size_t)g * H_DIM + h) * I_DIM))[i4];
        ushort4 o;
        o.x = f2bf(v.x); o.y = f2bf(v.y); o.z = f2bf(v.z); o.w = f2bf(v.w);
        ((ushort4*)(wdB + ((size_t)h * G_GRP + g) * I_DIM))[i4] = o;
    } else {                   // gate_w transpose [64][2048] -> [2048][64]
        int i = (b - 3 * NQB) * 256 + t;
        gwT[i] = gw[(i & 63) * H_DIM + (i >> 6)];
    }
}

// ---------------- gating: logits (f64 acc) + softmax + top8 + group softmax ----------------
__global__ __launch_bounds__(512) void k_gating(const float* __restrict__ x,
                                                const float* __restrict__ gwT,
                                                float* __restrict__ soft,
                                                float* __restrict__ scal) {
    __shared__ double smAcc[8][8][64];
    int t = threadIdx.x, wid = t >> 6, lane = t & 63;
    int n0 = blockIdx.x * 8;

    double acc[8];
#pragma unroll
    for (int k = 0; k < 8; ++k) acc[k] = 0.0;
    int h0 = wid * 256;
    for (int h = h0; h < h0 + 256; ++h) {
        float gv = gwT[h * 64 + lane];
#pragma unroll
        for (int tok = 0; tok < 8; ++tok)
            acc[tok] += (double)x[(size_t)(n0 + tok) * H_DIM + h] * (double)gv;
    }
#pragma unroll
    for (int tok = 0; tok < 8; ++tok) smAcc[wid][tok][lane] = acc[tok];
    __syncthreads();

    double lg = 0.0;
#pragma unroll
    for (int w2 = 0; w2 < 8; ++w2) lg += smAcc[w2][wid][lane];
    float logit = (float)lg;

    float mx = logit;
#pragma unroll
    for (int d = 1; d < 64; d <<= 1) mx = fmaxf(mx, __shfl_xor(mx, d));
    float ex = expf(logit - mx);
    float sm = ex;
#pragma unroll
    for (int d = 1; d < 64; d <<= 1) sm += __shfl_xor(sm, d);
    float prob = ex / sm;

    float cur = prob, w = 0.0f;
#pragma unroll
    for (int it = 0; it < 8; ++it) {
        float m = cur;
#pragma unroll
        for (int d = 1; d < 64; d <<= 1) m = fmaxf(m, __shfl_xor(m, d));
        unsigned long long msk = __ballot(cur == m);
        int first = __ffsll(msk) - 1;
        if (lane == first) { w = prob; cur = -1.0f; }
    }
    float wf = w;

    float s8 = wf;
#pragma unroll
    for (int d = 1; d < 8; d <<= 1) s8 += __shfl_xor(s8, d);
    float v = (wf == 0.0f) ? -1000000000.0f : wf;
    float m8 = v;
#pragma unroll
    for (int d = 1; d < 8; d <<= 1) m8 = fmaxf(m8, __shfl_xor(m8, d));
    float e8 = expf(v - m8);
    float q8 = e8;
#pragma unroll
    for (int d = 1; d < 8; d <<= 1) q8 += __shfl_xor(q8, d);

    int n = n0 + wid;
    soft[(size_t)n * 64 + lane] = e8 / q8;
    if ((lane & 7) == 0) scal[(size_t)n * 8 + (lane >> 3)] = s8;
}

// ------- xg[g][n][h] = bf16(x + soft.mu), vectorized: thread owns 4 h-cols, mu in regs -------
__global__ __launch_bounds__(256) void k_xg(const float* __restrict__ x,
                                            const float* __restrict__ muw,
                                            const float* __restrict__ soft,
                                            unsigned short* __restrict__ xg) {
    int g = blockIdx.z, h0 = blockIdx.y * 1024, n0 = blockIdx.x * 128;
    __shared__ float smSf[128][8];
    int t = threadIdx.x;
    {
        int r = t >> 1, s4 = (t & 1) * 4;
        float4 sv = *(const float4*)&soft[(size_t)(n0 + r) * 64 + g * 8 + s4];
        smSf[r][s4 + 0] = sv.x; smSf[r][s4 + 1] = sv.y;
        smSf[r][s4 + 2] = sv.z; smSf[r][s4 + 3] = sv.w;
    }
    int hh = t * 4;
    float mu[8][4];
#pragma unroll
    for (int j = 0; j < 4; ++j) {
        const float4* p = (const float4*)(muw + ((size_t)g * H_DIM + h0 + hh + j) * 8);
        float4 a = p[0], b = p[1];
        mu[0][j] = a.x; mu[1][j] = a.y; mu[2][j] = a.z; mu[3][j] = a.w;
        mu[4][j] = b.x; mu[5][j] = b.y; mu[6][j] = b.z; mu[7][j] = b.w;
    }
    __syncthreads();
    for (int r = 0; r < 128; ++r) {
        float4 xv = *(const float4*)&x[(size_t)(n0 + r) * H_DIM + h0 + hh];
        float c0 = xv.x, c1 = xv.y, c2 = xv.z, c3 = xv.w;
#pragma unroll
        for (int s = 0; s < 8; ++s) {
            float w = smSf[r][s];
            c0 += w * mu[s][0]; c1 += w * mu[s][1];
            c2 += w * mu[s][2]; c3 += w * mu[s][3];
        }
        ushort4 o;
        o.x = f2bf(c0); o.y = f2bf(c1); o.z = f2bf(c2); o.w = f2bf(c3);
        *(ushort4*)&xg[((size_t)g * N_TOK + n0 + r) * H_DIM + h0 + hh] = o;
    }
}

// ---- gemm1 fused: 128m x 64n tile, dual accumulators (gate+up), K=2048, BK=64 ----
// a'[n][g*I+i] = scal[n,g] * silu(xg_g @ Wg^T) * (xg_g @ Wu^T)   (bf16)
// Per wave: 4 m-frags x 2 n-frags x 2 outputs = 16 MFMA : 8 ds_read per kh (m97 ratio).
// Grid 2816 1-D; g = blk&7 (XCD pin); n-idx slow, m-idx fast (B n-slab stays L2-hot).
__global__ __launch_bounds__(256) void k_gemm1(const unsigned short* __restrict__ xg,
                                               const unsigned short* __restrict__ wg,
                                               const unsigned short* __restrict__ wu,
                                               const float* __restrict__ scal,
                                               unsigned short* __restrict__ aB) {
    int f = blockIdx.x;
    int g = f & 7, r = f >> 3;          // r in [0,352)
    int m0 = (r & 15) * 128;
    int n0 = (r >> 4) * 64;
    __shared__ __align__(16) unsigned short smA[8192];  // 128r x 64k = 16KB
    __shared__ __align__(16) unsigned short smG[4096];  // 64r x 64k = 8KB
    __shared__ __align__(16) unsigned short smU[4096];  // 8KB
    __shared__ float smS[128];
    int t = threadIdx.x, wid = t >> 6, lane = t & 63;
    int r16 = lane & 15, quad = lane >> 4;
    int wm = wid >> 1, wn = wid & 1;

    if (t < 128) smS[t] = scal[(size_t)(m0 + t) * 8 + g];

    const unsigned short* A  = xg + (size_t)g * N_TOK * H_DIM;
    const unsigned short* Bg = wg + (size_t)g * I_DIM * H_DIM;
    const unsigned short* Bu = wu + (size_t)g * I_DIM * H_DIM;

    f32x4 zero = {0.f, 0.f, 0.f, 0.f};
    f32x4 accg[4][2], accu[4][2];
#pragma unroll
    for (int mi = 0; mi < 4; ++mi)
#pragma unroll
        for (int ni = 0; ni < 2; ++ni) { accg[mi][ni] = zero; accu[mi][ni] = zero; }

    for (int k0 = 0; k0 < H_DIM; k0 += 64) {
#pragma unroll
        for (int j = 0; j < 4; ++j) {   // A: 16 issues
            int issue = wid * 4 + j;
            int s = issue * 64 + lane;
            int row = s >> 3;
            int c = (s & 7) ^ (row & 7);
            gl_lds16(A + (size_t)(m0 + row) * H_DIM + k0 + c * 8, &smA[issue * 512]);
        }
#pragma unroll
        for (int j = 0; j < 2; ++j) {   // G,U: 8 issues each
            int issue = wid * 2 + j;
            int s = issue * 64 + lane;
            int row = s >> 3;
            int c = (s & 7) ^ (row & 7);
            gl_lds16(Bg + (size_t)(n0 + row) * H_DIM + k0 + c * 8, &smG[issue * 512]);
            gl_lds16(Bu + (size_t)(n0 + row) * H_DIM + k0 + c * 8, &smU[issue * 512]);
        }
        __syncthreads();
#pragma unroll
        for (int kh = 0; kh < 2; ++kh) {
            int cc = kh * 4 + quad;
            bf16x8 af[4], bgf[2], buf_[2];
#pragma unroll
            for (int mi = 0; mi < 4; ++mi) af[mi] = lds_frag(smA, wm * 64 + mi * 16 + r16, cc);
#pragma unroll
            for (int ni = 0; ni < 2; ++ni) {
                int rw = wn * 32 + ni * 16 + r16;
                bgf[ni] = lds_frag(smG, rw, cc);
                buf_[ni] = lds_frag(smU, rw, cc);
            }
#pragma unroll
            for (int mi = 0; mi < 4; ++mi)
#pragma unroll
                for (int ni = 0; ni < 2; ++ni) {
                    accg[mi][ni] = __builtin_amdgcn_mfma_f32_16x16x32_bf16(af[mi], bgf[ni], accg[mi][ni], 0, 0, 0);
                    accu[mi][ni] = __builtin_amdgcn_mfma_f32_16x16x32_bf16(af[mi], buf_[ni], accu[mi][ni], 0, 0, 0);
                }
        }
        __syncthreads();
    }

#pragma unroll
    for (int mi = 0; mi < 4; ++mi)
#pragma unroll
        for (int ni = 0; ni < 2; ++ni)
#pragma unroll
            for (int rr = 0; rr < 4; ++rr) {
                int rl = wm * 64 + mi * 16 + quad * 4 + rr;
                int row = m0 + rl;
                int col = n0 + wn * 32 + ni * 16 + r16;
                float gv = accg[mi][ni][rr];
                float sv = gv / (1.0f + __expf(-gv));
                aB[((size_t)row * G_GRP + g) * I_DIM + col] = f2bf(sv * accu[mi][ni][rr] * smS[rl]);
            }
}

// ---------------- gemm2: y[n,h] = A'[n,:] . Wd'[h,:], K=11264, split-K=2 + atomicAdd ----------------
__global__ __launch_bounds__(256) void k_gemm2(const unsigned short* __restrict__ aB,
                                               const unsigned short* __restrict__ wd,
                                               float* __restrict__ out) {
    int m0 = blockIdx.x * 128, h0 = blockIdx.y * 128;
    int kbase = blockIdx.z * (KTOT / 2);
    __shared__ __align__(16) unsigned short smA[8192], smB[8192];
    int t = threadIdx.x, wid = t >> 6, lane = t & 63;
    int r16 = lane & 15, quad = lane >> 4;
    int wm = wid >> 1, wn = wid & 1;

    f32x4 zero = {0.f, 0.f, 0.f, 0.f};
    f32x4 acc[4][4];
#pragma unroll
    for (int mi = 0; mi < 4; ++mi)
#pragma unroll
        for (int ni = 0; ni < 4; ++ni) acc[mi][ni] = zero;

    for (int k0 = kbase; k0 < kbase + KTOT / 2; k0 += 64) {
#pragma unroll
        for (int j = 0; j < 4; ++j) {
            int issue = wid * 4 + j;
            int s = issue * 64 + lane;
            int row = s >> 3;
            int c = (s & 7) ^ (row & 7);
            gl_lds16(aB + (size_t)(m0 + row) * KTOT + k0 + c * 8, &smA[issue * 512]);
            gl_lds16(wd + (size_t)(h0 + row) * KTOT + k0 + c * 8, &smB[issue * 512]);
        }
        __syncthreads();
#pragma unroll
        for (int kh = 0; kh < 2; ++kh) {
            int cc = kh * 4 + quad;
            bf16x8 af[4], bf_[4];
#pragma unroll
            for (int mi = 0; mi < 4; ++mi) af[mi]  = lds_frag(smA, wm * 64 + mi * 16 + r16, cc);
#pragma unroll
            for (int ni = 0; ni < 4; ++ni) bf_[ni] = lds_frag(smB, wn * 64 + ni * 16 + r16, cc);
#pragma unroll
            for (int mi = 0; mi < 4; ++mi)
#pragma unroll
                for (int ni = 0; ni < 4; ++ni)
                    acc[mi][ni] = __builtin_amdgcn_mfma_f32_16x16x32_bf16(af[mi], bf_[ni], acc[mi][ni], 0, 0, 0);
        }
        __syncthreads();
    }

#pragma unroll
    for (int mi = 0; mi < 4; ++mi)
#pragma unroll
        for (int ni = 0; ni < 4; ++ni)
#pragma unroll
            for (int rr = 0; rr < 4; ++rr) {
                int row = m0 + wm * 64 + mi * 16 + quad * 4 + rr;
                int col = h0 + wn * 64 + ni * 16 + r16;
                atomicAdd(&out[(size_t)row * H_DIM + col], acc[mi][ni][rr]);
            }
}

extern "C" void kernel_launch(void* const* d_in, const int* in_sizes, int n_in,
                              void* d_out, int out_size, void* d_ws, size_t ws_size,
                              hipStream_t stream) {
    const float* x   = (const float*)d_in[0];
    const float* gw  = (const float*)d_in[1];
    const float* mu  = (const float*)d_in[2];
    const float* wgp = (const float*)d_in[3];
    const float* wup = (const float*)d_in[4];
    const float* wdp = (const float*)d_in[5];
    float* out = (float*)d_out;
    char* ws = (char*)d_ws;

    // workspace layout (241.1 MB total)
    float* gwT  = (float*)(ws + 0);                      // 512 KB
    float* soft = (float*)(ws + 524288);                 // 512 KB
    float* scal = (float*)(ws + 1048576);                // 64 KB
    unsigned short* wgB = (unsigned short*)(ws + 1114112);    // 44 MB [g][i][h]
    unsigned short* wuB = (unsigned short*)(ws + 47251456);   // 44 MB [g][i][h]
    unsigned short* wdB = (unsigned short*)(ws + 93388800);   // 44 MB [h][g*I+i]
    unsigned short* xg  = (unsigned short*)(ws + 139526144);  // 64 MB [g][n][h]
    unsigned short* aB  = (unsigned short*)(ws + 206635008);  // 44 MB [n][g*I+i]

    hipMemsetAsync(d_out, 0, (size_t)N_TOK * H_DIM * sizeof(float), stream);
    k_prep<<<3 * NQB + 512, 256, 0, stream>>>(gw, wgp, wup, wdp, gwT, wgB, wuB, wdB);
    k_gating<<<N_TOK / 8, 512, 0, stream>>>(x, gwT, soft, scal);
    k_xg<<<dim3(16, 2, 8), 256, 0, stream>>>(x, mu, soft, xg);
    k_gemm1<<<2816, 256, 0, stream>>>(xg, wgB, wuB, scal, aB);
    k_gemm2<<<dim3(16, 16, 2), 256, 0, stream>>>(aB, wdB, out);
}